// Round 16
// baseline (147.894 us; speedup 1.0000x reference)
//
#include <hip/hip_runtime.h>
#include <math.h>

#define SS 2048
#define NN 1024
#define DD 1024
#define HH 16
#define CONDD 128

typedef unsigned short ushort;
typedef unsigned int uint;
typedef __bf16 bf16x8 __attribute__((ext_vector_type(8)));
typedef float f32x4 __attribute__((ext_vector_type(4)));
typedef short s16x4 __attribute__((ext_vector_type(4)));
typedef ushort u16x8 __attribute__((ext_vector_type(8)));

// gelu tanh-approx via hardware exp2/rcp
__device__ __forceinline__ float gelu_fast(float x) {
    float t = x + 0.044715f * x * x * x;
    float e = __builtin_exp2f(-2.3022081446f * t);
    return x * __builtin_amdgcn_rcpf(1.0f + e);
}

__device__ __forceinline__ ushort f2bf(float x) {
    uint u = __float_as_uint(x);
    u += 0x7fff + ((u >> 16) & 1);
    return (ushort)(u >> 16);
}

__device__ __forceinline__ float bf2f(ushort u) {
    return __uint_as_float(((uint)u) << 16);
}

__device__ __forceinline__ float ldf(const float* p) { return *p; }
__device__ __forceinline__ float ldf(const ushort* p) { return bf2f(*p); }

__device__ __forceinline__ void gload16(const ushort* g, ushort* l) {
    __builtin_amdgcn_global_load_lds(
        (const __attribute__((address_space(1))) void*)g,
        (__attribute__((address_space(3))) void*)l, 16, 0, 0);
}

// counted vmcnt wait (literal required in asm)
template <int N>
__device__ __forceinline__ void wait_vm() {
    if constexpr (N == 0)      asm volatile("s_waitcnt vmcnt(0)" ::: "memory");
    else if constexpr (N == 2) asm volatile("s_waitcnt vmcnt(2)" ::: "memory");
    else if constexpr (N == 3) asm volatile("s_waitcnt vmcnt(3)" ::: "memory");
}

// 16x16x16 bf16 MFMA (PV step)
__device__ __forceinline__ f32x4 mfma16(s16x4 a, s16x4 b, f32x4 c) {
#if __has_builtin(__builtin_amdgcn_mfma_f32_16x16x16bf16_1k)
    return __builtin_amdgcn_mfma_f32_16x16x16bf16_1k(a, b, c, 0, 0, 0);
#else
    asm("v_mfma_f32_16x16x16_bf16 %0, %1, %2, %0" : "+v"(c) : "v"(a), "v"(b));
    return c;
#endif
}

// all 4 weight tensors -> one contiguous bf16 region (wq|wo|w1|w2)
__global__ void k_cast4(const float* __restrict__ s0, const float* __restrict__ s1,
                        const float* __restrict__ s2, const float* __restrict__ s3,
                        ushort* __restrict__ dst) {
    size_t gid = ((size_t)blockIdx.x * 256 + threadIdx.x) * 4;
    const float* src;
    size_t off;
    if (gid < (3ull << 20))      { src = s0; off = 0; }
    else if (gid < (4ull << 20)) { src = s1; off = 3ull << 20; }
    else if (gid < (8ull << 20)) { src = s2; off = 4ull << 20; }
    else                         { src = s3; off = 8ull << 20; }
    float4 v = *(const float4*)(src + (gid - off));
    ushort4 o = {f2bf(v.x), f2bf(v.y), f2bf(v.z), f2bf(v.w)};
    *(ushort4*)(dst + gid) = o;
}

// mods[6D] = adaLN_b + adaLN_w @ c
__global__ void k_adaln(const float* __restrict__ c, const float* __restrict__ w,
                        const float* __restrict__ b, float* __restrict__ mods) {
    int o = blockIdx.x * 256 + threadIdx.x;
    float s = b[o];
    const float* wr = w + (size_t)o * CONDD;
    for (int k = 0; k < CONDD; ++k) s += c[k] * wr[k];
    mods[o] = s;
}

// out(bf16)[row] = LN(x[row]) * w * (1 + mods[sc*D+:]) + mods[sh*D+:]
template <typename IT>
__global__ void k_ln_mod(const IT* __restrict__ x, const float* __restrict__ w,
                         const float* __restrict__ mods, int sh_idx, int sc_idx,
                         ushort* __restrict__ out) {
    int row = blockIdx.x;
    int tid = threadIdx.x;
    const IT* xr = x + (size_t)row * DD;
    float lx[4];
    float s = 0.f, s2 = 0.f;
    for (int i = 0; i < 4; ++i) {
        float v = ldf(&xr[tid + i * 256]);
        lx[i] = v; s += v; s2 += v * v;
    }
    __shared__ float rs[256], rs2[256];
    rs[tid] = s; rs2[tid] = s2; __syncthreads();
    for (int off = 128; off > 0; off >>= 1) {
        if (tid < off) { rs[tid] += rs[tid + off]; rs2[tid] += rs2[tid + off]; }
        __syncthreads();
    }
    float mu = rs[0] * (1.0f / DD);
    float var = rs2[0] * (1.0f / DD) - mu * mu;
    float rstd = rsqrtf(var + 1e-5f);
    const float* sh = mods + sh_idx * DD;
    const float* sc = mods + sc_idx * DD;
    ushort* orow = out + (size_t)row * DD;
    for (int i = 0; i < 4; ++i) {
        int d = tid + i * 256;
        orow[d] = f2bf((lx[i] - mu) * rstd * w[d] * (1.0f + sc[d]) + sh[d]);
    }
}

// C[M,N] = A[M,K](bf16) @ W[N,K](bf16)^T, fp32 accum, fused epilogue.
// 512 threads / 8 waves (2x4), tile TM x TN, BK=64, mfma_f32_16x16x32_bf16,
// XOR-swizzled LDS (0 conflicts), 3-buffer counted-vmcnt pipeline,
// L2-supertiled XCD work order, hoisted addressing, K-loop unrolled x3.
// R16: wave-parity sub-phase STAGGER — odd waves process K-sub-phases in
// swapped order (via offA/offB row swap at init; static indices), so at any
// instant ~half the waves ds_read while half run MFMA: breaks the
// post-barrier LDS read convoy (LDS unit was ~50% idle).
template <int TM, int TN, int MODE, typename OT>
__global__ __launch_bounds__(512) void k_gemm_mfma(
        const ushort* __restrict__ A, const ushort* __restrict__ W,
        const float* __restrict__ bias, const float* __restrict__ gate,
        const void* __restrict__ resid, OT* __restrict__ C,
        int M, int Nout, int K) {
    constexpr int WTM = TM / 2, WTN = TN / 4;
    constexpr int FM = WTM / 16, FN = WTN / 16;
    constexpr int BUFE = (TM + TN) * 64;      // ushorts per buffer
    constexpr int NA = TM / 64, NB = TN / 64; // gloads per wave per stage
    constexpr int LPW = NA + NB;
    __shared__ ushort lds[3 * BUFE];

    int tid = threadIdx.x;
    int lane = tid & 63, wave = tid >> 6;     // 8 waves
    int wr = wave >> 2, wc = wave & 3;        // 2 x 4 wave grid
    int l15 = lane & 15, l4 = lane >> 4;

    // XCD chunk + 2-level supertile (L2-resident W panels + A m-groups)
    int orig = blockIdx.y * gridDim.x + blockIdx.x;
    int xcd = orig & 7;
    int idx = orig >> 3;
    int Nx = gridDim.x >> 3;
    int grp = 8 * Nx;
    int sm = idx / grp;
    int r = idx % grp;
    int ng = r >> 3;
    int mi2 = r & 7;
    int m0 = (sm * 8 + mi2) * TM;
    int n0 = (xcd * Nx + ng) * TN;

    f32x4 acc[FM][FN] = {};

    // ---- hoisted addressing ----
    const ushort* pA[NA];
    const ushort* pB[NB];
    int dA[NA], dB[NB];                       // LDS stage dests (wave-uniform)
#pragma unroll
    for (int i = 0; i < NA; ++i) {
        int cb = (wave * NA + i) * 64;
        int ch = cb + lane;
        int row = ch >> 3;
        int kc = (ch & 7) ^ (row & 7);
        pA[i] = A + (size_t)(m0 + row) * K + kc * 8;
        dA[i] = cb * 8;
    }
#pragma unroll
    for (int i = 0; i < NB; ++i) {
        int cb = (wave * NB + i) * 64;
        int ch = cb + lane;
        int row = ch >> 3;
        int kc = (ch & 7) ^ (row & 7);
        pB[i] = W + (size_t)(n0 + row) * K + kc * 8;
        dB[i] = TM * 64 + cb * 8;
    }
    int offA[2][FM], offB[2][FN];             // ds_read frag offsets (per-lane)
#pragma unroll
    for (int sub = 0; sub < 2; ++sub) {
#pragma unroll
        for (int mi = 0; mi < FM; ++mi) {
            int row = wr * WTM + mi * 16 + l15;
            int pos = ((sub << 2) | l4) ^ (row & 7);
            offA[sub][mi] = row * 64 + pos * 8;
        }
#pragma unroll
        for (int ni = 0; ni < FN; ++ni) {
            int row = wc * WTN + ni * 16 + l15;
            int pos = ((sub << 2) | l4) ^ (row & 7);
            offB[sub][ni] = TM * 64 + row * 64 + pos * 8;
        }
    }
    // wave-parity stagger: odd waves consume sub-phases in swapped order
    if (wave & 1) {
#pragma unroll
        for (int mi = 0; mi < FM; ++mi) {
            int t = offA[0][mi]; offA[0][mi] = offA[1][mi]; offA[1][mi] = t;
        }
#pragma unroll
        for (int ni = 0; ni < FN; ++ni) {
            int t = offB[0][ni]; offB[0][ni] = offB[1][ni]; offB[1][ni] = t;
        }
    }

    auto stage = [&](int buf) {               // buf is a literal at call sites
        ushort* base = lds + buf * BUFE;
#pragma unroll
        for (int i = 0; i < NA; ++i) { gload16(pA[i], base + dA[i]); pA[i] += 64; }
#pragma unroll
        for (int i = 0; i < NB; ++i) { gload16(pB[i], base + dB[i]); pB[i] += 64; }
    };

    auto compute = [&](int buf) {
        const ushort* base = lds + buf * BUFE;
#pragma unroll
        for (int sub = 0; sub < 2; ++sub) {
            bf16x8 af[FM], bw[FN];
#pragma unroll
            for (int mi = 0; mi < FM; ++mi)
                af[mi] = *(const bf16x8*)&base[offA[sub][mi]];
#pragma unroll
            for (int ni = 0; ni < FN; ++ni)
                bw[ni] = *(const bf16x8*)&base[offB[sub][ni]];
            __builtin_amdgcn_s_setprio(1);
#pragma unroll
            for (int mi = 0; mi < FM; ++mi)
#pragma unroll
                for (int ni = 0; ni < FN; ++ni)
                    acc[mi][ni] = __builtin_amdgcn_mfma_f32_16x16x32_bf16(
                        af[mi], bw[ni], acc[mi][ni], 0, 0, 0);
            __builtin_amdgcn_s_setprio(0);
        }
    };

    int nk = K >> 6;
    auto iter = [&](int t, int bufc, int bufs) {
        if (t + 1 < nk) wait_vm<LPW>(); else wait_vm<0>();
        __builtin_amdgcn_s_barrier();
        __builtin_amdgcn_sched_barrier(0);
        if (t + 2 < nk) stage(bufs);
        compute(bufc);
    };

    stage(0);
    stage(1);
    for (int t = 0; t < nk; t += 3) {
        iter(t, 0, 2);
        if (t + 1 < nk) iter(t + 1, 1, 0);
        if (t + 2 < nk) iter(t + 2, 2, 1);
    }

    const float*  rf = (const float*)resid;
    const ushort* rb = (const ushort*)resid;
#pragma unroll
    for (int mi = 0; mi < FM; ++mi) {
#pragma unroll
        for (int r2 = 0; r2 < 4; ++r2) {
            int m = m0 + wr * WTM + mi * 16 + l4 * 4 + r2;
#pragma unroll
            for (int ni = 0; ni < FN; ++ni) {
                int n = n0 + wc * WTN + ni * 16 + l15;
                float v = acc[mi][ni][r2];
                if (MODE == 1) v = gate[n] * v + rf[(size_t)m * Nout + n];
                if (MODE == 2) v = gelu_fast(v + bias[n]);
                if (MODE == 3) v = gate[n] * (v + bias[n]) + bf2f(rb[(size_t)m * Nout + n]);
                if (sizeof(OT) == 2) C[(size_t)m * Nout + n] = (OT)f2bf(v);
                else                 C[(size_t)m * Nout + n] = (OT)v;
            }
        }
    }
}

// RoPE on bf16 qkv [s][3][H][64] -> qb[s][D] (scaled by 0.125*log2e), kb[s][D],
// vT[h][d][s] (transposed via LDS). RoPE applied to q, k AND v; pos = s mod N.
__global__ void k_rope2(const ushort* __restrict__ qkvb, const float* __restrict__ cosT,
                        const float* __restrict__ sinT, ushort* __restrict__ qb,
                        ushort* __restrict__ kb, ushort* __restrict__ vT) {
    __shared__ ushort vt[64][65];
    int h = blockIdx.x & 15;
    int st = blockIdx.x >> 4;
    int s0 = st * 64;
    int tid = threadIdx.x;
#pragma unroll
    for (int i = 0; i < 8; ++i) {
        int idx = tid + i * 256;
        int sl = idx >> 5, j = idx & 31;
        int s = s0 + sl;
        int pos = s & (NN - 1);
        float cv = cosT[pos * 32 + j], sv = sinT[pos * 32 + j];
        const ushort* row = qkvb + (size_t)s * 3072 + h * 64;
        float x1 = bf2f(row[j]), x2 = bf2f(row[j + 32]);
        qb[(size_t)s * DD + h * 64 + j]      = f2bf((x1 * cv - x2 * sv) * 0.18033688011f);
        qb[(size_t)s * DD + h * 64 + j + 32] = f2bf((x2 * cv + x1 * sv) * 0.18033688011f);
        x1 = bf2f(row[1024 + j]); x2 = bf2f(row[1024 + j + 32]);
        kb[(size_t)s * DD + h * 64 + j]      = f2bf(x1 * cv - x2 * sv);
        kb[(size_t)s * DD + h * 64 + j + 32] = f2bf(x2 * cv + x1 * sv);
        x1 = bf2f(row[2048 + j]); x2 = bf2f(row[2048 + j + 32]);
        vt[sl][j]      = f2bf(x1 * cv - x2 * sv);
        vt[sl][j + 32] = f2bf(x2 * cv + x1 * sv);
    }
    __syncthreads();
    int drow = tid >> 2, sc = (tid & 3) * 16;
    u16x8 a, b;
#pragma unroll
    for (int i = 0; i < 8; ++i) { a[i] = vt[sc + i][drow]; b[i] = vt[sc + 8 + i][drow]; }
    size_t base = (size_t)(h * 64 + drow) * SS + s0 + sc;
    *(u16x8*)&vT[base] = a;
    *(u16x8*)&vT[base + 8] = b;
}

// MFMA flash attention, split-softmax: 4 waves per (head, bq) block.
struct KVTile { bf16x8 k0, k1; s16x4 v0, v1, v2, v3; };

__global__ __launch_bounds__(256) void k_attn4(
        const ushort* __restrict__ qb, const ushort* __restrict__ kb,
        const ushort* __restrict__ vT, ushort* __restrict__ o) {
    __shared__ float Ml[2][4][16], Ll[2][4][16];
    __shared__ float Ob[2][4][16][68];          // [state][wave][q][dim(+pad)]

    int id = blockIdx.x;
    int h = id & 15;
    int bq = 63 - (id >> 4);          // heavy-first
    int tid = threadIdx.x;
    int wave = tid >> 6;
    int lane = tid & 63;
    int l15 = lane & 15, l4 = lane >> 4;
    int hb = h * 64;

    const int q0A = bq * 16, q0B = NN + bq * 16;
    bf16x8 qA0 = *(const bf16x8*)&qb[(size_t)(q0A + l15) * DD + hb + l4 * 8];
    bf16x8 qA1 = *(const bf16x8*)&qb[(size_t)(q0A + l15) * DD + hb + 32 + l4 * 8];
    bf16x8 qB0 = *(const bf16x8*)&qb[(size_t)(q0B + l15) * DD + hb + l4 * 8];
    bf16x8 qB1 = *(const bf16x8*)&qb[(size_t)(q0B + l15) * DD + hb + 32 + l4 * 8];

    float mA = -1e30f, lA = 0.f, mB = -1e30f, lB = 0.f;
    f32x4 oA0 = {}, oA1 = {}, oA2 = {}, oA3 = {};
    f32x4 oB0 = {}, oB1 = {}, oB2 = {}, oB3 = {};

    auto loadT = [&](int kbase) {
        KVTile t;
        const ushort* kr = kb + (size_t)(kbase + l15) * DD + hb + l4 * 8;
        t.k0 = *(const bf16x8*)kr;
        t.k1 = *(const bf16x8*)(kr + 32);
        const ushort* vr = vT + (size_t)(hb + l15) * SS + kbase + l4 * 4;
        t.v0 = *(const s16x4*)vr;
        t.v1 = *(const s16x4*)(vr + 16 * SS);
        t.v2 = *(const s16x4*)(vr + 32 * SS);
        t.v3 = *(const s16x4*)(vr + 48 * SS);
        return t;
    };

    auto step = [&](const KVTile& t, bf16x8 Q0, bf16x8 Q1, float& m, float& l,
                    f32x4& O0, f32x4& O1, f32x4& O2, f32x4& O3) {
        f32x4 s = {};
        __builtin_amdgcn_s_setprio(1);
        s = __builtin_amdgcn_mfma_f32_16x16x32_bf16(t.k0, Q0, s, 0, 0, 0);
        s = __builtin_amdgcn_mfma_f32_16x16x32_bf16(t.k1, Q1, s, 0, 0, 0);
        __builtin_amdgcn_s_setprio(0);
        float tm = fmaxf(fmaxf(s[0], s[1]), fmaxf(s[2], s[3]));
        tm = fmaxf(tm, __shfl_xor(tm, 16));
        tm = fmaxf(tm, __shfl_xor(tm, 32));
        if (!__all(tm <= m + 8.0f)) {
            float mn = fmaxf(m, tm);
            float alpha = exp2f(m - mn);
            l *= alpha;
            O0 *= alpha; O1 *= alpha; O2 *= alpha; O3 *= alpha;
            m = mn;
        }
        float p0 = exp2f(s[0] - m), p1 = exp2f(s[1] - m);
        float p2 = exp2f(s[2] - m), p3 = exp2f(s[3] - m);
        float rsum = (p0 + p1) + (p2 + p3);
        rsum += __shfl_xor(rsum, 16);
        rsum += __shfl_xor(rsum, 32);
        l += rsum;
        s16x4 pf;
        pf[0] = (short)f2bf(p0); pf[1] = (short)f2bf(p1);
        pf[2] = (short)f2bf(p2); pf[3] = (short)f2bf(p3);
        __builtin_amdgcn_s_setprio(1);
        O0 = mfma16(t.v0, pf, O0);
        O1 = mfma16(t.v1, pf, O1);
        O2 = mfma16(t.v2, pf, O2);
        O3 = mfma16(t.v3, pf, O3);
        __builtin_amdgcn_s_setprio(0);
    };

    if (wave == 0) {
        KVTile td = loadT(q0A);
        step(td, qA0, qA1, mA, lA, oA0, oA1, oA2, oA3);
    }
    KVTile cur, nxt;
    if (wave <= bq) cur = loadT(NN + wave * 16);
    for (int t = wave; t <= bq; t += 4) {
        int tn = t + 4;
        if (tn <= bq) nxt = loadT(NN + tn * 16);
        if (t < bq) step(cur, qA0, qA1, mA, lA, oA0, oA1, oA2, oA3);
        step(cur, qB0, qB1, mB, lB, oB0, oB1, oB2, oB3);
        cur = nxt;
    }

    if (l4 == 0) {
        Ml[0][wave][l15] = mA; Ll[0][wave][l15] = lA;
        Ml[1][wave][l15] = mB; Ll[1][wave][l15] = lB;
    }
    *(f32x4*)&Ob[0][wave][l15][l4 * 4]      = oA0;
    *(f32x4*)&Ob[0][wave][l15][l4 * 4 + 16] = oA1;
    *(f32x4*)&Ob[0][wave][l15][l4 * 4 + 32] = oA2;
    *(f32x4*)&Ob[0][wave][l15][l4 * 4 + 48] = oA3;
    *(f32x4*)&Ob[1][wave][l15][l4 * 4]      = oB0;
    *(f32x4*)&Ob[1][wave][l15][l4 * 4 + 16] = oB1;
    *(f32x4*)&Ob[1][wave][l15][l4 * 4 + 32] = oB2;
    *(f32x4*)&Ob[1][wave][l15][l4 * 4 + 48] = oB3;
    __syncthreads();

    int s = tid >> 7;
    int qr = (tid >> 3) & 15;
    int db = (tid & 7) * 8;
    float m0 = Ml[s][0][qr], m1 = Ml[s][1][qr], m2 = Ml[s][2][qr], m3 = Ml[s][3][qr];
    float ms = fmaxf(fmaxf(m0, m1), fmaxf(m2, m3));
    float a0 = exp2f(m0 - ms), a1 = exp2f(m1 - ms);
    float a2 = exp2f(m2 - ms), a3 = exp2f(m3 - ms);
    float lt = a0 * Ll[s][0][qr] + a1 * Ll[s][1][qr] + a2 * Ll[s][2][qr] + a3 * Ll[s][3][qr];
    float inv = 1.0f / lt;
    int q0s = (s == 0) ? q0A : q0B;
    u16x8 outv;
#pragma unroll
    for (int j = 0; j < 8; ++j) {
        float v = a0 * Ob[s][0][qr][db + j] + a1 * Ob[s][1][qr][db + j] +
                  a2 * Ob[s][2][qr][db + j] + a3 * Ob[s][3][qr][db + j];
        outv[j] = f2bf(v * inv);
    }
    *(u16x8*)&o[(size_t)(q0s + qr) * DD + hb + db] = outv;
}

extern "C" void kernel_launch(void* const* d_in, const int* in_sizes, int n_in,
                              void* d_out, int out_size, void* d_ws, size_t ws_size,
                              hipStream_t stream) {
    const float* x          = (const float*)d_in[0];
    const float* c          = (const float*)d_in[1];
    const float* cosT       = (const float*)d_in[2];
    const float* sinT       = (const float*)d_in[3];
    const float* norm1_w    = (const float*)d_in[4];
    const float* qkv_w      = (const float*)d_in[5];
    const float* attn_out_w = (const float*)d_in[6];
    const float* norm2_w    = (const float*)d_in[7];
    const float* mlp_w1     = (const float*)d_in[8];
    const float* mlp_b1     = (const float*)d_in[9];
    const float* mlp_w2     = (const float*)d_in[10];
    const float* mlp_b2     = (const float*)d_in[11];
    const float* adaLN_w    = (const float*)d_in[12];
    const float* adaLN_b    = (const float*)d_in[13];
    float* out = (float*)d_out;

    char* p = (char*)d_ws;
    float*  mods = (float*)p;   p += 6 * DD * 4;
    ushort* qkvb = (ushort*)p;  p += (size_t)SS * 3 * DD * 2;   // 12 MB
    ushort* qb   = (ushort*)p;  p += (size_t)SS * DD * 2;       // 4 MB
    ushort* kb   = (ushort*)p;  p += (size_t)SS * DD * 2;
    ushort* vT   = (ushort*)p;  p += (size_t)SS * DD * 2;
    ushort* x2b  = (ushort*)p;  p += (size_t)SS * DD * 2;       // bf16 spine
    ushort* hbuf = (ushort*)p;  p += (size_t)SS * DD * 2;
    ushort* obuf = (ushort*)p;  p += (size_t)SS * DD * 2;
    ushort* wq   = (ushort*)p;  p += (size_t)3 * DD * DD * 2;   // contiguous:
    ushort* wo   = (ushort*)p;  p += (size_t)DD * DD * 2;       //   wq|wo|w1|w2
    ushort* w1   = (ushort*)p;  p += (size_t)4 * DD * DD * 2;
    ushort* w2   = (ushort*)p;  p += (size_t)4 * DD * DD * 2;
    ushort* m1   = qkvb;   // alias: qkvb(12MB)+qb(4MB) dead after k_attn4

    k_cast4<<<(12 << 20) / 1024, 256, 0, stream>>>(qkv_w, attn_out_w, mlp_w1, mlp_w2, wq);

    k_adaln<<<6 * DD / 256, 256, 0, stream>>>(c, adaLN_w, adaLN_b, mods);
    k_ln_mod<float><<<SS, 256, 0, stream>>>(x, norm1_w, mods, 0, 1, hbuf);

    dim3 g1(3 * DD / 128, SS / 64);    // 24 x 32 = 768 blocks
    k_gemm_mfma<64, 128, 0, ushort><<<g1, 512, 0, stream>>>(
        hbuf, wq, nullptr, nullptr, nullptr, qkvb, SS, 3 * DD, DD);
    k_rope2<<<512, 256, 0, stream>>>(qkvb, cosT, sinT, qb, kb, vT);
    k_attn4<<<HH * 64, 256, 0, stream>>>(qb, kb, vT, obuf);

    dim3 g2(DD / 64, SS / 64);         // 16 x 32 = 512 blocks
    k_gemm_mfma<64, 64, 1, ushort><<<g2, 512, 0, stream>>>(
        obuf, wo, nullptr, mods + 2 * DD, x, x2b, SS, DD, DD);
    k_ln_mod<ushort><<<SS, 256, 0, stream>>>(x2b, norm2_w, mods, 3, 4, hbuf);

    dim3 g3(4 * DD / 128, SS / 64);    // 32 x 32 = 1024 blocks
    k_gemm_mfma<64, 128, 2, ushort><<<g3, 512, 0, stream>>>(
        hbuf, w1, mlp_b1, nullptr, nullptr, m1, SS, 4 * DD, DD);
    dim3 g4(DD / 64, SS / 64);         // 16 x 32 = 512 blocks
    k_gemm_mfma<64, 64, 3, float><<<g4, 512, 0, stream>>>(
        m1, w2, mlp_b2, mods + 5 * DD, x2b, out, SS, DD, 4 * DD);
}

// Round 17
// 146.961 us; speedup vs baseline: 1.0063x; 1.0063x over previous
//
#include <hip/hip_runtime.h>
#include <math.h>

#define SS 2048
#define NN 1024
#define DD 1024
#define HH 16
#define CONDD 128

typedef unsigned short ushort;
typedef unsigned int uint;
typedef __bf16 bf16x8 __attribute__((ext_vector_type(8)));
typedef float f32x4 __attribute__((ext_vector_type(4)));
typedef short s16x4 __attribute__((ext_vector_type(4)));
typedef ushort u16x8 __attribute__((ext_vector_type(8)));

// gelu tanh-approx via hardware exp2/rcp
__device__ __forceinline__ float gelu_fast(float x) {
    float t = x + 0.044715f * x * x * x;
    float e = __builtin_exp2f(-2.3022081446f * t);
    return x * __builtin_amdgcn_rcpf(1.0f + e);
}

__device__ __forceinline__ ushort f2bf(float x) {
    uint u = __float_as_uint(x);
    u += 0x7fff + ((u >> 16) & 1);
    return (ushort)(u >> 16);
}

__device__ __forceinline__ float bf2f(ushort u) {
    return __uint_as_float(((uint)u) << 16);
}

__device__ __forceinline__ float ldf(const float* p) { return *p; }
__device__ __forceinline__ float ldf(const ushort* p) { return bf2f(*p); }

__device__ __forceinline__ void gload16(const ushort* g, ushort* l) {
    __builtin_amdgcn_global_load_lds(
        (const __attribute__((address_space(1))) void*)g,
        (__attribute__((address_space(3))) void*)l, 16, 0, 0);
}

// counted vmcnt wait (literal required in asm)
template <int N>
__device__ __forceinline__ void wait_vm() {
    if constexpr (N == 0)      asm volatile("s_waitcnt vmcnt(0)" ::: "memory");
    else if constexpr (N == 2) asm volatile("s_waitcnt vmcnt(2)" ::: "memory");
    else if constexpr (N == 3) asm volatile("s_waitcnt vmcnt(3)" ::: "memory");
    else if constexpr (N == 6) asm volatile("s_waitcnt vmcnt(6)" ::: "memory");
}

// 16x16x16 bf16 MFMA (PV step)
__device__ __forceinline__ f32x4 mfma16(s16x4 a, s16x4 b, f32x4 c) {
#if __has_builtin(__builtin_amdgcn_mfma_f32_16x16x16bf16_1k)
    return __builtin_amdgcn_mfma_f32_16x16x16bf16_1k(a, b, c, 0, 0, 0);
#else
    asm("v_mfma_f32_16x16x16_bf16 %0, %1, %2, %0" : "+v"(c) : "v"(a), "v"(b));
    return c;
#endif
}

// all 4 weight tensors -> one contiguous bf16 region (wq|wo|w1|w2)
__global__ void k_cast4(const float* __restrict__ s0, const float* __restrict__ s1,
                        const float* __restrict__ s2, const float* __restrict__ s3,
                        ushort* __restrict__ dst) {
    size_t gid = ((size_t)blockIdx.x * 256 + threadIdx.x) * 4;
    const float* src;
    size_t off;
    if (gid < (3ull << 20))      { src = s0; off = 0; }
    else if (gid < (4ull << 20)) { src = s1; off = 3ull << 20; }
    else if (gid < (8ull << 20)) { src = s2; off = 4ull << 20; }
    else                         { src = s3; off = 8ull << 20; }
    float4 v = *(const float4*)(src + (gid - off));
    ushort4 o = {f2bf(v.x), f2bf(v.y), f2bf(v.z), f2bf(v.w)};
    *(ushort4*)(dst + gid) = o;
}

// mods[6D] = adaLN_b + adaLN_w @ c
__global__ void k_adaln(const float* __restrict__ c, const float* __restrict__ w,
                        const float* __restrict__ b, float* __restrict__ mods) {
    int o = blockIdx.x * 256 + threadIdx.x;
    float s = b[o];
    const float* wr = w + (size_t)o * CONDD;
    for (int k = 0; k < CONDD; ++k) s += c[k] * wr[k];
    mods[o] = s;
}

// out(bf16)[row] = LN(x[row]) * w * (1 + mods[sc*D+:]) + mods[sh*D+:]
template <typename IT>
__global__ void k_ln_mod(const IT* __restrict__ x, const float* __restrict__ w,
                         const float* __restrict__ mods, int sh_idx, int sc_idx,
                         ushort* __restrict__ out) {
    int row = blockIdx.x;
    int tid = threadIdx.x;
    const IT* xr = x + (size_t)row * DD;
    float lx[4];
    float s = 0.f, s2 = 0.f;
    for (int i = 0; i < 4; ++i) {
        float v = ldf(&xr[tid + i * 256]);
        lx[i] = v; s += v; s2 += v * v;
    }
    __shared__ float rs[256], rs2[256];
    rs[tid] = s; rs2[tid] = s2; __syncthreads();
    for (int off = 128; off > 0; off >>= 1) {
        if (tid < off) { rs[tid] += rs[tid + off]; rs2[tid] += rs2[tid + off]; }
        __syncthreads();
    }
    float mu = rs[0] * (1.0f / DD);
    float var = rs2[0] * (1.0f / DD) - mu * mu;
    float rstd = rsqrtf(var + 1e-5f);
    const float* sh = mods + sh_idx * DD;
    const float* sc = mods + sc_idx * DD;
    ushort* orow = out + (size_t)row * DD;
    for (int i = 0; i < 4; ++i) {
        int d = tid + i * 256;
        orow[d] = f2bf((lx[i] - mu) * rstd * w[d] * (1.0f + sc[d]) + sh[d]);
    }
}

// C[M,N] = A[M,K](bf16) @ W[N,K](bf16)^T, fp32 accum, fused epilogue.
// 512 threads / 8 waves (2x4), tile TM x TN, BK=64, mfma_f32_16x16x32_bf16,
// XOR-swizzled LDS (0 conflicts), 3-buffer counted-vmcnt pipeline,
// L2-supertiled XCD work order, hoisted addressing, K-loop unrolled x3.
// R17: mlp1 uses TM=128 x TN=256 (wave tile 64x64, FM=FN=4): block-level
// LDS intensity 16.4 -> 23.8 FLOP/B, staging bytes & barriers per FLOP
// halve; grid 256 = exactly 1 block/CU (LDS 144 KB, pipeline unchanged).
template <int TM, int TN, int MODE, typename OT>
__global__ __launch_bounds__(512) void k_gemm_mfma(
        const ushort* __restrict__ A, const ushort* __restrict__ W,
        const float* __restrict__ bias, const float* __restrict__ gate,
        const void* __restrict__ resid, OT* __restrict__ C,
        int M, int Nout, int K) {
    constexpr int WTM = TM / 2, WTN = TN / 4;
    constexpr int FM = WTM / 16, FN = WTN / 16;
    constexpr int BUFE = (TM + TN) * 64;      // ushorts per buffer
    constexpr int NA = TM / 64, NB = TN / 64; // gloads per wave per stage
    constexpr int LPW = NA + NB;
    __shared__ ushort lds[3 * BUFE];

    int tid = threadIdx.x;
    int lane = tid & 63, wave = tid >> 6;     // 8 waves
    int wr = wave >> 2, wc = wave & 3;        // 2 x 4 wave grid
    int l15 = lane & 15, l4 = lane >> 4;

    // XCD chunk + 2-level supertile (L2-resident W panels + A m-groups)
    int orig = blockIdx.y * gridDim.x + blockIdx.x;
    int xcd = orig & 7;
    int idx = orig >> 3;
    int Nx = gridDim.x >> 3;
    int grp = 8 * Nx;
    int sm = idx / grp;
    int r = idx % grp;
    int ng = r >> 3;
    int mi2 = r & 7;
    int m0 = (sm * 8 + mi2) * TM;
    int n0 = (xcd * Nx + ng) * TN;

    f32x4 acc[FM][FN] = {};

    // ---- hoisted addressing ----
    const ushort* pA[NA];
    const ushort* pB[NB];
    int dA[NA], dB[NB];                       // LDS stage dests (wave-uniform)
#pragma unroll
    for (int i = 0; i < NA; ++i) {
        int cb = (wave * NA + i) * 64;
        int ch = cb + lane;
        int row = ch >> 3;
        int kc = (ch & 7) ^ (row & 7);
        pA[i] = A + (size_t)(m0 + row) * K + kc * 8;
        dA[i] = cb * 8;
    }
#pragma unroll
    for (int i = 0; i < NB; ++i) {
        int cb = (wave * NB + i) * 64;
        int ch = cb + lane;
        int row = ch >> 3;
        int kc = (ch & 7) ^ (row & 7);
        pB[i] = W + (size_t)(n0 + row) * K + kc * 8;
        dB[i] = TM * 64 + cb * 8;
    }
    int offA[2][FM], offB[2][FN];             // ds_read frag offsets (per-lane)
#pragma unroll
    for (int sub = 0; sub < 2; ++sub) {
#pragma unroll
        for (int mi = 0; mi < FM; ++mi) {
            int row = wr * WTM + mi * 16 + l15;
            int pos = ((sub << 2) | l4) ^ (row & 7);
            offA[sub][mi] = row * 64 + pos * 8;
        }
#pragma unroll
        for (int ni = 0; ni < FN; ++ni) {
            int row = wc * WTN + ni * 16 + l15;
            int pos = ((sub << 2) | l4) ^ (row & 7);
            offB[sub][ni] = TM * 64 + row * 64 + pos * 8;
        }
    }
    // wave-parity stagger: odd waves consume sub-phases in swapped order
    if (wave & 1) {
#pragma unroll
        for (int mi = 0; mi < FM; ++mi) {
            int t = offA[0][mi]; offA[0][mi] = offA[1][mi]; offA[1][mi] = t;
        }
#pragma unroll
        for (int ni = 0; ni < FN; ++ni) {
            int t = offB[0][ni]; offB[0][ni] = offB[1][ni]; offB[1][ni] = t;
        }
    }

    auto stage = [&](int buf) {               // buf is a literal at call sites
        ushort* base = lds + buf * BUFE;
#pragma unroll
        for (int i = 0; i < NA; ++i) { gload16(pA[i], base + dA[i]); pA[i] += 64; }
#pragma unroll
        for (int i = 0; i < NB; ++i) { gload16(pB[i], base + dB[i]); pB[i] += 64; }
    };

    auto compute = [&](int buf) {
        const ushort* base = lds + buf * BUFE;
#pragma unroll
        for (int sub = 0; sub < 2; ++sub) {
            bf16x8 af[FM], bw[FN];
#pragma unroll
            for (int mi = 0; mi < FM; ++mi)
                af[mi] = *(const bf16x8*)&base[offA[sub][mi]];
#pragma unroll
            for (int ni = 0; ni < FN; ++ni)
                bw[ni] = *(const bf16x8*)&base[offB[sub][ni]];
            __builtin_amdgcn_s_setprio(1);
#pragma unroll
            for (int mi = 0; mi < FM; ++mi)
#pragma unroll
                for (int ni = 0; ni < FN; ++ni)
                    acc[mi][ni] = __builtin_amdgcn_mfma_f32_16x16x32_bf16(
                        af[mi], bw[ni], acc[mi][ni], 0, 0, 0);
            __builtin_amdgcn_s_setprio(0);
        }
    };

    int nk = K >> 6;
    auto iter = [&](int t, int bufc, int bufs) {
        if (t + 1 < nk) wait_vm<LPW>(); else wait_vm<0>();
        __builtin_amdgcn_s_barrier();
        __builtin_amdgcn_sched_barrier(0);
        if (t + 2 < nk) stage(bufs);
        compute(bufc);
    };

    stage(0);
    stage(1);
    for (int t = 0; t < nk; t += 3) {
        iter(t, 0, 2);
        if (t + 1 < nk) iter(t + 1, 1, 0);
        if (t + 2 < nk) iter(t + 2, 2, 1);
    }

    const float*  rf = (const float*)resid;
    const ushort* rb = (const ushort*)resid;
#pragma unroll
    for (int mi = 0; mi < FM; ++mi) {
#pragma unroll
        for (int r2 = 0; r2 < 4; ++r2) {
            int m = m0 + wr * WTM + mi * 16 + l4 * 4 + r2;
#pragma unroll
            for (int ni = 0; ni < FN; ++ni) {
                int n = n0 + wc * WTN + ni * 16 + l15;
                float v = acc[mi][ni][r2];
                if (MODE == 1) v = gate[n] * v + rf[(size_t)m * Nout + n];
                if (MODE == 2) v = gelu_fast(v + bias[n]);
                if (MODE == 3) v = gate[n] * (v + bias[n]) + bf2f(rb[(size_t)m * Nout + n]);
                if (sizeof(OT) == 2) C[(size_t)m * Nout + n] = (OT)f2bf(v);
                else                 C[(size_t)m * Nout + n] = (OT)v;
            }
        }
    }
}

// RoPE on bf16 qkv [s][3][H][64] -> qb[s][D] (scaled by 0.125*log2e), kb[s][D],
// vT[h][d][s] (transposed via LDS). RoPE applied to q, k AND v; pos = s mod N.
__global__ void k_rope2(const ushort* __restrict__ qkvb, const float* __restrict__ cosT,
                        const float* __restrict__ sinT, ushort* __restrict__ qb,
                        ushort* __restrict__ kb, ushort* __restrict__ vT) {
    __shared__ ushort vt[64][65];
    int h = blockIdx.x & 15;
    int st = blockIdx.x >> 4;
    int s0 = st * 64;
    int tid = threadIdx.x;
#pragma unroll
    for (int i = 0; i < 8; ++i) {
        int idx = tid + i * 256;
        int sl = idx >> 5, j = idx & 31;
        int s = s0 + sl;
        int pos = s & (NN - 1);
        float cv = cosT[pos * 32 + j], sv = sinT[pos * 32 + j];
        const ushort* row = qkvb + (size_t)s * 3072 + h * 64;
        float x1 = bf2f(row[j]), x2 = bf2f(row[j + 32]);
        qb[(size_t)s * DD + h * 64 + j]      = f2bf((x1 * cv - x2 * sv) * 0.18033688011f);
        qb[(size_t)s * DD + h * 64 + j + 32] = f2bf((x2 * cv + x1 * sv) * 0.18033688011f);
        x1 = bf2f(row[1024 + j]); x2 = bf2f(row[1024 + j + 32]);
        kb[(size_t)s * DD + h * 64 + j]      = f2bf(x1 * cv - x2 * sv);
        kb[(size_t)s * DD + h * 64 + j + 32] = f2bf(x2 * cv + x1 * sv);
        x1 = bf2f(row[2048 + j]); x2 = bf2f(row[2048 + j + 32]);
        vt[sl][j]      = f2bf(x1 * cv - x2 * sv);
        vt[sl][j + 32] = f2bf(x2 * cv + x1 * sv);
    }
    __syncthreads();
    int drow = tid >> 2, sc = (tid & 3) * 16;
    u16x8 a, b;
#pragma unroll
    for (int i = 0; i < 8; ++i) { a[i] = vt[sc + i][drow]; b[i] = vt[sc + 8 + i][drow]; }
    size_t base = (size_t)(h * 64 + drow) * SS + s0 + sc;
    *(u16x8*)&vT[base] = a;
    *(u16x8*)&vT[base + 8] = b;
}

// MFMA flash attention, split-softmax: 4 waves per (head, bq) block.
struct KVTile { bf16x8 k0, k1; s16x4 v0, v1, v2, v3; };

__global__ __launch_bounds__(256) void k_attn4(
        const ushort* __restrict__ qb, const ushort* __restrict__ kb,
        const ushort* __restrict__ vT, ushort* __restrict__ o) {
    __shared__ float Ml[2][4][16], Ll[2][4][16];
    __shared__ float Ob[2][4][16][68];          // [state][wave][q][dim(+pad)]

    int id = blockIdx.x;
    int h = id & 15;
    int bq = 63 - (id >> 4);          // heavy-first
    int tid = threadIdx.x;
    int wave = tid >> 6;
    int lane = tid & 63;
    int l15 = lane & 15, l4 = lane >> 4;
    int hb = h * 64;

    const int q0A = bq * 16, q0B = NN + bq * 16;
    bf16x8 qA0 = *(const bf16x8*)&qb[(size_t)(q0A + l15) * DD + hb + l4 * 8];
    bf16x8 qA1 = *(const bf16x8*)&qb[(size_t)(q0A + l15) * DD + hb + 32 + l4 * 8];
    bf16x8 qB0 = *(const bf16x8*)&qb[(size_t)(q0B + l15) * DD + hb + l4 * 8];
    bf16x8 qB1 = *(const bf16x8*)&qb[(size_t)(q0B + l15) * DD + hb + 32 + l4 * 8];

    float mA = -1e30f, lA = 0.f, mB = -1e30f, lB = 0.f;
    f32x4 oA0 = {}, oA1 = {}, oA2 = {}, oA3 = {};
    f32x4 oB0 = {}, oB1 = {}, oB2 = {}, oB3 = {};

    auto loadT = [&](int kbase) {
        KVTile t;
        const ushort* kr = kb + (size_t)(kbase + l15) * DD + hb + l4 * 8;
        t.k0 = *(const bf16x8*)kr;
        t.k1 = *(const bf16x8*)(kr + 32);
        const ushort* vr = vT + (size_t)(hb + l15) * SS + kbase + l4 * 4;
        t.v0 = *(const s16x4*)vr;
        t.v1 = *(const s16x4*)(vr + 16 * SS);
        t.v2 = *(const s16x4*)(vr + 32 * SS);
        t.v3 = *(const s16x4*)(vr + 48 * SS);
        return t;
    };

    auto step = [&](const KVTile& t, bf16x8 Q0, bf16x8 Q1, float& m, float& l,
                    f32x4& O0, f32x4& O1, f32x4& O2, f32x4& O3) {
        f32x4 s = {};
        __builtin_amdgcn_s_setprio(1);
        s = __builtin_amdgcn_mfma_f32_16x16x32_bf16(t.k0, Q0, s, 0, 0, 0);
        s = __builtin_amdgcn_mfma_f32_16x16x32_bf16(t.k1, Q1, s, 0, 0, 0);
        __builtin_amdgcn_s_setprio(0);
        float tm = fmaxf(fmaxf(s[0], s[1]), fmaxf(s[2], s[3]));
        tm = fmaxf(tm, __shfl_xor(tm, 16));
        tm = fmaxf(tm, __shfl_xor(tm, 32));
        if (!__all(tm <= m + 8.0f)) {
            float mn = fmaxf(m, tm);
            float alpha = exp2f(m - mn);
            l *= alpha;
            O0 *= alpha; O1 *= alpha; O2 *= alpha; O3 *= alpha;
            m = mn;
        }
        float p0 = exp2f(s[0] - m), p1 = exp2f(s[1] - m);
        float p2 = exp2f(s[2] - m), p3 = exp2f(s[3] - m);
        float rsum = (p0 + p1) + (p2 + p3);
        rsum += __shfl_xor(rsum, 16);
        rsum += __shfl_xor(rsum, 32);
        l += rsum;
        s16x4 pf;
        pf[0] = (short)f2bf(p0); pf[1] = (short)f2bf(p1);
        pf[2] = (short)f2bf(p2); pf[3] = (short)f2bf(p3);
        __builtin_amdgcn_s_setprio(1);
        O0 = mfma16(t.v0, pf, O0);
        O1 = mfma16(t.v1, pf, O1);
        O2 = mfma16(t.v2, pf, O2);
        O3 = mfma16(t.v3, pf, O3);
        __builtin_amdgcn_s_setprio(0);
    };

    if (wave == 0) {
        KVTile td = loadT(q0A);
        step(td, qA0, qA1, mA, lA, oA0, oA1, oA2, oA3);
    }
    KVTile cur, nxt;
    if (wave <= bq) cur = loadT(NN + wave * 16);
    for (int t = wave; t <= bq; t += 4) {
        int tn = t + 4;
        if (tn <= bq) nxt = loadT(NN + tn * 16);
        if (t < bq) step(cur, qA0, qA1, mA, lA, oA0, oA1, oA2, oA3);
        step(cur, qB0, qB1, mB, lB, oB0, oB1, oB2, oB3);
        cur = nxt;
    }

    if (l4 == 0) {
        Ml[0][wave][l15] = mA; Ll[0][wave][l15] = lA;
        Ml[1][wave][l15] = mB; Ll[1][wave][l15] = lB;
    }
    *(f32x4*)&Ob[0][wave][l15][l4 * 4]      = oA0;
    *(f32x4*)&Ob[0][wave][l15][l4 * 4 + 16] = oA1;
    *(f32x4*)&Ob[0][wave][l15][l4 * 4 + 32] = oA2;
    *(f32x4*)&Ob[0][wave][l15][l4 * 4 + 48] = oA3;
    *(f32x4*)&Ob[1][wave][l15][l4 * 4]      = oB0;
    *(f32x4*)&Ob[1][wave][l15][l4 * 4 + 16] = oB1;
    *(f32x4*)&Ob[1][wave][l15][l4 * 4 + 32] = oB2;
    *(f32x4*)&Ob[1][wave][l15][l4 * 4 + 48] = oB3;
    __syncthreads();

    int s = tid >> 7;
    int qr = (tid >> 3) & 15;
    int db = (tid & 7) * 8;
    float m0 = Ml[s][0][qr], m1 = Ml[s][1][qr], m2 = Ml[s][2][qr], m3 = Ml[s][3][qr];
    float ms = fmaxf(fmaxf(m0, m1), fmaxf(m2, m3));
    float a0 = exp2f(m0 - ms), a1 = exp2f(m1 - ms);
    float a2 = exp2f(m2 - ms), a3 = exp2f(m3 - ms);
    float lt = a0 * Ll[s][0][qr] + a1 * Ll[s][1][qr] + a2 * Ll[s][2][qr] + a3 * Ll[s][3][qr];
    float inv = 1.0f / lt;
    int q0s = (s == 0) ? q0A : q0B;
    u16x8 outv;
#pragma unroll
    for (int j = 0; j < 8; ++j) {
        float v = a0 * Ob[s][0][qr][db + j] + a1 * Ob[s][1][qr][db + j] +
                  a2 * Ob[s][2][qr][db + j] + a3 * Ob[s][3][qr][db + j];
        outv[j] = f2bf(v * inv);
    }
    *(u16x8*)&o[(size_t)(q0s + qr) * DD + hb + db] = outv;
}

extern "C" void kernel_launch(void* const* d_in, const int* in_sizes, int n_in,
                              void* d_out, int out_size, void* d_ws, size_t ws_size,
                              hipStream_t stream) {
    const float* x          = (const float*)d_in[0];
    const float* c          = (const float*)d_in[1];
    const float* cosT       = (const float*)d_in[2];
    const float* sinT       = (const float*)d_in[3];
    const float* norm1_w    = (const float*)d_in[4];
    const float* qkv_w      = (const float*)d_in[5];
    const float* attn_out_w = (const float*)d_in[6];
    const float* norm2_w    = (const float*)d_in[7];
    const float* mlp_w1     = (const float*)d_in[8];
    const float* mlp_b1     = (const float*)d_in[9];
    const float* mlp_w2     = (const float*)d_in[10];
    const float* mlp_b2     = (const float*)d_in[11];
    const float* adaLN_w    = (const float*)d_in[12];
    const float* adaLN_b    = (const float*)d_in[13];
    float* out = (float*)d_out;

    char* p = (char*)d_ws;
    float*  mods = (float*)p;   p += 6 * DD * 4;
    ushort* qkvb = (ushort*)p;  p += (size_t)SS * 3 * DD * 2;   // 12 MB
    ushort* qb   = (ushort*)p;  p += (size_t)SS * DD * 2;       // 4 MB
    ushort* kb   = (ushort*)p;  p += (size_t)SS * DD * 2;
    ushort* vT   = (ushort*)p;  p += (size_t)SS * DD * 2;
    ushort* x2b  = (ushort*)p;  p += (size_t)SS * DD * 2;       // bf16 spine
    ushort* hbuf = (ushort*)p;  p += (size_t)SS * DD * 2;
    ushort* obuf = (ushort*)p;  p += (size_t)SS * DD * 2;
    ushort* wq   = (ushort*)p;  p += (size_t)3 * DD * DD * 2;   // contiguous:
    ushort* wo   = (ushort*)p;  p += (size_t)DD * DD * 2;       //   wq|wo|w1|w2
    ushort* w1   = (ushort*)p;  p += (size_t)4 * DD * DD * 2;
    ushort* w2   = (ushort*)p;  p += (size_t)4 * DD * DD * 2;
    ushort* m1   = qkvb;   // alias: qkvb(12MB)+qb(4MB) dead after k_attn4

    k_cast4<<<(12 << 20) / 1024, 256, 0, stream>>>(qkv_w, attn_out_w, mlp_w1, mlp_w2, wq);

    k_adaln<<<6 * DD / 256, 256, 0, stream>>>(c, adaLN_w, adaLN_b, mods);
    k_ln_mod<float><<<SS, 256, 0, stream>>>(x, norm1_w, mods, 0, 1, hbuf);

    dim3 g1(3 * DD / 128, SS / 64);    // 24 x 32 = 768 blocks
    k_gemm_mfma<64, 128, 0, ushort><<<g1, 512, 0, stream>>>(
        hbuf, wq, nullptr, nullptr, nullptr, qkvb, SS, 3 * DD, DD);
    k_rope2<<<512, 256, 0, stream>>>(qkvb, cosT, sinT, qb, kb, vT);
    k_attn4<<<HH * 64, 256, 0, stream>>>(qb, kb, vT, obuf);

    dim3 g2(DD / 64, SS / 64);         // 16 x 32 = 512 blocks
    k_gemm_mfma<64, 64, 1, ushort><<<g2, 512, 0, stream>>>(
        obuf, wo, nullptr, mods + 2 * DD, x, x2b, SS, DD, DD);
    k_ln_mod<ushort><<<SS, 256, 0, stream>>>(x2b, norm2_w, mods, 3, 4, hbuf);

    dim3 g3(4 * DD / 256, SS / 128);   // 16 x 16 = 256 blocks, 1/CU
    k_gemm_mfma<128, 256, 2, ushort><<<g3, 512, 0, stream>>>(
        hbuf, w1, mlp_b1, nullptr, nullptr, m1, SS, 4 * DD, DD);
    dim3 g4(DD / 64, SS / 64);         // 16 x 32 = 512 blocks
    k_gemm_mfma<64, 64, 3, float><<<g4, 512, 0, stream>>>(
        m1, w2, mlp_b2, mods + 5 * DD, x2b, out, SS, DD, 4 * DD);
}